// Round 6
// baseline (92.103 us; speedup 1.0000x reference)
//
#include <hip/hip_runtime.h>
#include <math.h>

#define T_SEQ 1024
#define DIN 128
#define NH 64

// ---------------------------------------------------------------------------
// k1: Bx[b][h][t] = sum_j B[h][j] * x[b][t][j]
// grid 256 x 256. Wave w owns h in [16w,16w+16); lane owns one (b,t) row.
// B is read via WAVE-UNIFORM addresses (readfirstlane) -> s_load_dwordx4 into
// SGPRs; v_fma reads the SGPR operand directly. No LDS, no per-lane B
// materialization (that was ~10us of VGPR-write bandwidth in the old version).
// ---------------------------------------------------------------------------
__global__ __launch_bounds__(256) void k_gemm(const float* __restrict__ x,
                                              const float* __restrict__ Bm,
                                              float* __restrict__ bx) {
    const int tid = threadIdx.x;
    const int wave = __builtin_amdgcn_readfirstlane(tid >> 6);  // uniform
    const int lane = tid & 63;
    const int row = blockIdx.x * 64 + lane;     // flat (b,t) row
    const int b = row >> 10, t = row & 1023;
    const float4* xr = reinterpret_cast<const float4*>(x + (size_t)row * DIN);
    const float4* Br = reinterpret_cast<const float4*>(Bm + (size_t)wave * 16 * DIN);

    float acc[16];
#pragma unroll
    for (int i = 0; i < 16; ++i) acc[i] = 0.f;

#pragma unroll 2
    for (int jc = 0; jc < DIN / 4; ++jc) {
        const float4 xv = xr[jc];
#pragma unroll
        for (int hh = 0; hh < 16; ++hh) {
            const float4 bv = Br[hh * 32 + jc];   // uniform addr -> SGPR load
            acc[hh] = fmaf(xv.x, bv.x,
                      fmaf(xv.y, bv.y,
                      fmaf(xv.z, bv.z,
                      fmaf(xv.w, bv.w, acc[hh]))));
        }
    }
#pragma unroll
    for (int hh = 0; hh < 16; ++hh)
        bx[((size_t)((b << 6) + (wave << 4) + hh) << 10) + t] = acc[hh];
}

// ---------------------------------------------------------------------------
// k2: fused scan + transpose. grid 64 x 1024.
// Block = (b, group of 16 consecutive h). Wave w scans (b, hg*16+w):
//   h_t = lam*h_{t-1} + u_t, h_{-1} = 1   (lam = exp(-exp(nu)+i*theta))
// lane l owns t in [16l,16l+16): local serial scan -> 64-lane Hillis-Steele
// with factor lam^16 -> exclusive carry + lam^(16l) initial state.
// Results go to LDS [16h][1028t] with q-staggered quad positions
// (2-way bank traffic on both write and read = free), then written to
// out[b][t][hg*16 .. +15 | 64+...] as full 64B-line float4 stores.
// ---------------------------------------------------------------------------
__global__ __launch_bounds__(1024) void k_scan_tr(const float* __restrict__ nu,
                                                  const float* __restrict__ theta,
                                                  const float* __restrict__ R,
                                                  float* __restrict__ out) {
    __shared__ float sR[16][1028];
    __shared__ float sI[16][1028];
    const int tid = threadIdx.x;
    const int w = __builtin_amdgcn_readfirstlane(tid >> 6);  // 0..15
    const int lane = tid & 63;
    const int b = blockIdx.x >> 2;
    const int hg = blockIdx.x & 3;
    const int h = hg * 16 + w;
    const int wid = (b << 6) + h;

    const float env = expf(nu[h]);
    const float th = theta[h];
    float s1, c1; sincosf(th, &s1, &c1);
    const float mag1 = expf(-env);
    const float lr = mag1 * c1, li = mag1 * s1;

    const float4* rowR = reinterpret_cast<const float4*>(R + ((size_t)wid << 10));
    float pr[16], pi[16];
#pragma unroll
    for (int q = 0; q < 4; ++q) {
        const float4 u4 = rowR[lane * 4 + q];
        pr[4 * q + 0] = u4.x; pr[4 * q + 1] = u4.y;
        pr[4 * q + 2] = u4.z; pr[4 * q + 3] = u4.w;
    }

    // local inclusive scan over 16 steps
    float sr = 0.f, si = 0.f;
#pragma unroll
    for (int i = 0; i < 16; ++i) {
        const float u = pr[i];
        const float nr = lr * sr - li * si + u;
        const float ni = lr * si + li * sr;
        pr[i] = nr; pi[i] = ni;
        sr = nr; si = ni;
    }

    // wave scan of chunk aggregates, factor f = lam^16 (power-doubled)
    float fs_, fc_; sincosf(16.f * th, &fs_, &fc_);
    const float fmag = expf(-16.f * env);
    float dr = fmag * fc_, di = fmag * fs_;
    float vr = sr, vi = si;
#pragma unroll
    for (int d = 1; d < 64; d <<= 1) {
        const float orr = __shfl_up(vr, d, 64);
        const float oii = __shfl_up(vi, d, 64);
        if (lane >= d) {
            vr += dr * orr - di * oii;
            vi += dr * oii + di * orr;
        }
        const float t2r = dr * dr - di * di;
        const float t2i = 2.f * dr * di;
        dr = t2r; di = t2i;
    }

    // exclusive carry + initial-state term lam^(16*lane)
    float cr = __shfl_up(vr, 1, 64);
    float ci = __shfl_up(vi, 1, 64);
    if (lane == 0) { cr = 0.f; ci = 0.f; }
    float gs_, gc_; sincosf(16.f * (float)lane * th, &gs_, &gc_);
    const float gmag = expf(-16.f * (float)lane * env);
    const float gr = cr + gmag * gc_;
    const float gi = ci + gmag * gs_;

    // h_{16l+i} = lam^{i+1} * G + P_i
    float lpr = lr, lpi = li;
#pragma unroll
    for (int i = 0; i < 16; ++i) {
        const float hr = lpr * gr - lpi * gi + pr[i];
        const float hi = lpr * gi + lpi * gr + pi[i];
        pr[i] = hr; pi[i] = hi;
        const float nr = lpr * lr - lpi * li;
        const float ni = lpr * li + lpi * lr;
        lpr = nr; lpi = ni;
    }

    // LDS deposit: quad q of lane l lands at position 16l + 4*((q+l)&3).
#pragma unroll
    for (int q = 0; q < 4; ++q) {
        const int pos = 16 * lane + 4 * ((q + lane) & 3);
        *reinterpret_cast<float4*>(&sR[w][pos]) =
            make_float4(pr[4 * q + 0], pr[4 * q + 1], pr[4 * q + 2], pr[4 * q + 3]);
        *reinterpret_cast<float4*>(&sI[w][pos]) =
            make_float4(pi[4 * q + 0], pi[4 * q + 1], pi[4 * q + 2], pi[4 * q + 3]);
    }
    __syncthreads();

    // readout: 8 float4 per thread; k<4 -> Re, k>=4 -> Im.
    const size_t ob = (size_t)b * (T_SEQ * 128) + hg * 16;
#pragma unroll
    for (int k = 0; k < 8; ++k) {
        const int part = k >> 2;                 // 0 = Re, 1 = Im
        const int f2 = tid + (k & 3) * 1024;     // 0..4095
        const int c = f2 & 3;                    // h-quad within the 16
        const int t = f2 >> 2;                   // 0..1023
        // inverse of the q-stagger: data for time t sits at...
        const int pos = (t & ~15) | ((((t >> 2) + (t >> 4)) & 3) << 2) | (t & 3);
        float4 v;
        if (part == 0) {
            v.x = sR[4 * c + 0][pos]; v.y = sR[4 * c + 1][pos];
            v.z = sR[4 * c + 2][pos]; v.w = sR[4 * c + 3][pos];
        } else {
            v.x = sI[4 * c + 0][pos]; v.y = sI[4 * c + 1][pos];
            v.z = sI[4 * c + 2][pos]; v.w = sI[4 * c + 3][pos];
        }
        *reinterpret_cast<float4*>(&out[ob + (size_t)t * 128 + part * 64 + 4 * c]) = v;
    }
}

extern "C" void kernel_launch(void* const* d_in, const int* in_sizes, int n_in,
                              void* d_out, int out_size, void* d_ws, size_t ws_size,
                              hipStream_t stream) {
    const float* x  = (const float*)d_in[0];
    const float* Bm = (const float*)d_in[1];
    const float* nu = (const float*)d_in[2];
    const float* th = (const float*)d_in[3];
    float* out = (float*)d_out;

    float* R = (float*)d_ws;              // 1M floats: Bx[b][h][t]

    k_gemm   <<<256, 256, 0, stream>>>(x, Bm, R);
    k_scan_tr<<< 64, 1024, 0, stream>>>(nu, th, R, out);
}

// Round 8
// 90.188 us; speedup vs baseline: 1.0212x; 1.0212x over previous
//
#include <hip/hip_runtime.h>
#include <math.h>

#define T_SEQ 1024
#define DIN 128
#define NH 64

// ---------------------------------------------------------------------------
// k1: Bx[b][h][t] = sum_j B[h][j] * x[b][t][j]
// grid 256 x 256. Wave w owns h in [16w,16w+16); lane owns one (b,t) row.
// B read via wave-uniform addresses -> scalar/broadcast path, no LDS staging.
// (measured: passed round 6; unchanged this round)
// ---------------------------------------------------------------------------
__global__ __launch_bounds__(256) void k_gemm(const float* __restrict__ x,
                                              const float* __restrict__ Bm,
                                              float* __restrict__ bx) {
    const int tid = threadIdx.x;
    const int wave = __builtin_amdgcn_readfirstlane(tid >> 6);  // uniform
    const int lane = tid & 63;
    const int row = blockIdx.x * 64 + lane;     // flat (b,t) row
    const int b = row >> 10, t = row & 1023;
    const float4* xr = reinterpret_cast<const float4*>(x + (size_t)row * DIN);
    const float4* Br = reinterpret_cast<const float4*>(Bm + (size_t)wave * 16 * DIN);

    float acc[16];
#pragma unroll
    for (int i = 0; i < 16; ++i) acc[i] = 0.f;

#pragma unroll 2
    for (int jc = 0; jc < DIN / 4; ++jc) {
        const float4 xv = xr[jc];
#pragma unroll
        for (int hh = 0; hh < 16; ++hh) {
            const float4 bv = Br[hh * 32 + jc];   // uniform addr
            acc[hh] = fmaf(xv.x, bv.x,
                      fmaf(xv.y, bv.y,
                      fmaf(xv.z, bv.z,
                      fmaf(xv.w, bv.w, acc[hh]))));
        }
    }
#pragma unroll
    for (int hh = 0; hh < 16; ++hh)
        bx[((size_t)((b << 6) + (wave << 4) + hh) << 10) + t] = acc[hh];
}

// ---------------------------------------------------------------------------
// k2: fused scan + transpose. grid 128 x 512  (was 64 x 1024).
// Block = (b, group of 8 h). Wave w in [0,8) scans (b, hg*8+w):
//   h_t = lam*h_{t-1} + u_t, h_{-1} = 1   (lam = exp(-exp(nu)+i*theta))
// lane l owns t in [16l,16l+16): local serial scan -> 64-lane Hillis-Steele
// with factor lam^16 -> exclusive carry + lam^(16l) initial state.
// LDS [8][1028] x2 (66 KB -> 2 blocks/CU); q-staggered quad deposit (2-way
// free); readout writes out[b][t][hg*8+4c.. | 64+...] as 32B chunks
// (2 adjacent lanes cover 32B contiguous; banks covered exactly 2x = free).
// ---------------------------------------------------------------------------
__global__ __launch_bounds__(512) void k_scan_tr(const float* __restrict__ nu,
                                                 const float* __restrict__ theta,
                                                 const float* __restrict__ R,
                                                 float* __restrict__ out) {
    __shared__ float sR[8][1028];
    __shared__ float sI[8][1028];
    const int tid = threadIdx.x;
    const int w = __builtin_amdgcn_readfirstlane(tid >> 6);  // 0..7
    const int lane = tid & 63;
    const int b = blockIdx.x >> 3;
    const int hg = blockIdx.x & 7;
    const int h = hg * 8 + w;
    const int wid = (b << 6) + h;

    const float env = expf(nu[h]);
    const float th = theta[h];
    float s1, c1; sincosf(th, &s1, &c1);
    const float mag1 = expf(-env);
    const float lr = mag1 * c1, li = mag1 * s1;

    const float4* rowR = reinterpret_cast<const float4*>(R + ((size_t)wid << 10));
    float pr[16], pi[16];
#pragma unroll
    for (int q = 0; q < 4; ++q) {
        const float4 u4 = rowR[lane * 4 + q];
        pr[4 * q + 0] = u4.x; pr[4 * q + 1] = u4.y;
        pr[4 * q + 2] = u4.z; pr[4 * q + 3] = u4.w;
    }

    // local inclusive scan over 16 steps
    float sr = 0.f, si = 0.f;
#pragma unroll
    for (int i = 0; i < 16; ++i) {
        const float u = pr[i];
        const float nr = lr * sr - li * si + u;
        const float ni = lr * si + li * sr;
        pr[i] = nr; pi[i] = ni;
        sr = nr; si = ni;
    }

    // wave scan of chunk aggregates, factor f = lam^16 (power-doubled)
    float fs_, fc_; sincosf(16.f * th, &fs_, &fc_);
    const float fmag = expf(-16.f * env);
    float dr = fmag * fc_, di = fmag * fs_;
    float vr = sr, vi = si;
#pragma unroll
    for (int d = 1; d < 64; d <<= 1) {
        const float orr = __shfl_up(vr, d, 64);
        const float oii = __shfl_up(vi, d, 64);
        if (lane >= d) {
            vr += dr * orr - di * oii;
            vi += dr * oii + di * orr;
        }
        const float t2r = dr * dr - di * di;
        const float t2i = 2.f * dr * di;
        dr = t2r; di = t2i;
    }

    // exclusive carry + initial-state term lam^(16*lane)
    float cr = __shfl_up(vr, 1, 64);
    float ci = __shfl_up(vi, 1, 64);
    if (lane == 0) { cr = 0.f; ci = 0.f; }
    float gs_, gc_; sincosf(16.f * (float)lane * th, &gs_, &gc_);
    const float gmag = expf(-16.f * (float)lane * env);
    const float gr = cr + gmag * gc_;
    const float gi = ci + gmag * gs_;

    // h_{16l+i} = lam^{i+1} * G + P_i
    float lpr = lr, lpi = li;
#pragma unroll
    for (int i = 0; i < 16; ++i) {
        const float hr = lpr * gr - lpi * gi + pr[i];
        const float hi = lpr * gi + lpi * gr + pi[i];
        pr[i] = hr; pi[i] = hi;
        const float nr = lpr * lr - lpi * li;
        const float ni = lpr * li + lpi * lr;
        lpr = nr; lpi = ni;
    }

    // LDS deposit: quad q of lane l lands at position 16l + 4*((q+l)&3).
#pragma unroll
    for (int q = 0; q < 4; ++q) {
        const int pos = 16 * lane + 4 * ((q + lane) & 3);
        *reinterpret_cast<float4*>(&sR[w][pos]) =
            make_float4(pr[4 * q + 0], pr[4 * q + 1], pr[4 * q + 2], pr[4 * q + 3]);
        *reinterpret_cast<float4*>(&sI[w][pos]) =
            make_float4(pi[4 * q + 0], pi[4 * q + 1], pi[4 * q + 2], pi[4 * q + 3]);
    }
    __syncthreads();

    // readout: 8h x 1024t x 2 parts = 4096 float4; 8 per thread.
    // k<4 -> Re, k>=4 -> Im. f2 in [0,2048): c = f2&1 (4-h quad), t = f2>>1.
    const size_t ob = (size_t)b * (T_SEQ * 128) + hg * 8;
#pragma unroll
    for (int k = 0; k < 8; ++k) {
        const int part = k >> 2;                 // 0 = Re, 1 = Im
        const int f2 = tid + (k & 3) * 512;      // 0..2047
        const int c = f2 & 1;                    // h-quad within the 8
        const int t = f2 >> 1;                   // 0..1023
        // inverse of the q-stagger: data for time t sits at...
        const int pos = (t & ~15) | ((((t >> 2) + (t >> 4)) & 3) << 2) | (t & 3);
        float4 v;
        if (part == 0) {
            v.x = sR[4 * c + 0][pos]; v.y = sR[4 * c + 1][pos];
            v.z = sR[4 * c + 2][pos]; v.w = sR[4 * c + 3][pos];
        } else {
            v.x = sI[4 * c + 0][pos]; v.y = sI[4 * c + 1][pos];
            v.z = sI[4 * c + 2][pos]; v.w = sI[4 * c + 3][pos];
        }
        *reinterpret_cast<float4*>(&out[ob + (size_t)t * 128 + part * 64 + 4 * c]) = v;
    }
}

extern "C" void kernel_launch(void* const* d_in, const int* in_sizes, int n_in,
                              void* d_out, int out_size, void* d_ws, size_t ws_size,
                              hipStream_t stream) {
    const float* x  = (const float*)d_in[0];
    const float* Bm = (const float*)d_in[1];
    const float* nu = (const float*)d_in[2];
    const float* th = (const float*)d_in[3];
    float* out = (float*)d_out;

    float* R = (float*)d_ws;              // 1M floats: Bx[b][h][t]

    k_gemm   <<<256, 256, 0, stream>>>(x, Bm, R);
    k_scan_tr<<<128, 512, 0, stream>>>(nu, th, R, out);
}